// Round 2
// baseline (2007.850 us; speedup 1.0000x reference)
//
#include <hip/hip_runtime.h>
#include <hip/hip_bf16.h>

// Problem constants
#define BATCH   64
#define CHAN    384
#define HW      1024
#define SM_PB   (HW * HW)          // score elements per batch = 1048576
#define OUT_OFF 576                // action floats before score matrix
#define KTOP    1024
#define NBUCKET 4096
#define CAND_CAP 8192
#define KG      12                 // 384 / 32 k-groups
#define BAND_DELTA 1e-4f
#define BAND_CAP 64

// Workspace byte offsets (low region, always available)
#define WS_INV_CUR   0
#define WS_INV_GOAL  262144
#define WS_HIST      524288
#define WS_CNT       1572864
#define WS_TBUF      1573120
#define WS_CAND      1573376
#define WS_FEATS     5767680
#define WS_H1        6554112
#define WS_H2        6816256
// f16 hi/lo K-major planes (fast path only)
#define WS_PLANES    8388608
#define PLANE_ELEMS  (64ULL*12*1024*32)          // 25165824 f16 per plane
#define PLANE_BYTES  (PLANE_ELEMS*2)             // 50331648
#define WS_FAST_NEED (WS_PLANES + 4ULL*PLANE_BYTES)  // ~209.7 MB

typedef _Float16 v8h __attribute__((ext_vector_type(8)));
typedef float    v4f __attribute__((ext_vector_type(4)));

#define GLDS16(gp, lp) \
  __builtin_amdgcn_global_load_lds( \
      (const __attribute__((address_space(1))) unsigned int*)(gp), \
      (__attribute__((address_space(3))) unsigned int*)(lp), 16, 0, 0)

__device__ __forceinline__ unsigned mono_key(float f) {
    unsigned u = __float_as_uint(f);
    return u ^ ((u & 0x80000000u) ? 0xFFFFFFFFu : 0x80000000u);
}
__device__ __forceinline__ float key_to_float(unsigned k) {
    unsigned u = (k & 0x80000000u) ? (k ^ 0x80000000u) : ~k;
    return __uint_as_float(u);
}

// ---------------- 1. per-location inverse L2 norms over channels ----------
__global__ void norm_kernel(const float* __restrict__ cur,
                            const float* __restrict__ goal,
                            float* __restrict__ inv_cur,
                            float* __restrict__ inv_goal) {
    const int p = blockIdx.x * 256 + threadIdx.x;
    const int b = blockIdx.y;
    const float* pc = cur  + (size_t)b * CHAN * HW + p;
    const float* pg = goal + (size_t)b * CHAN * HW + p;
    float sc = 0.f, sg = 0.f;
    for (int c = 0; c < CHAN; ++c) {
        float vc = pc[c * HW];
        float vg = pg[c * HW];
        sc += vc * vc;
        sg += vg * vg;
    }
    inv_cur[b * HW + p]  = 1.0f / fmaxf(sqrtf(sc), 1e-12f);
    inv_goal[b * HW + p] = 1.0f / fmaxf(sqrtf(sg), 1e-12f);
}

// ---------------- 1b. transpose + f16 hi/lo split (fast path) -------------
// out layout per plane: [b][kg][m][kw]  (kw=32 contiguous), values scaled x64
__global__ __launch_bounds__(256)
void prep_kernel(const float* __restrict__ cur,
                 const float* __restrict__ goal,
                 _Float16* __restrict__ ph_cur, _Float16* __restrict__ pl_cur,
                 _Float16* __restrict__ ph_goal, _Float16* __restrict__ pl_goal) {
    const int mt = blockIdx.x;            // 0..15 (64-wide m tile)
    const int kg = blockIdx.y;            // 0..11
    const int b  = blockIdx.z & 63;
    const int tensor = blockIdx.z >> 6;
    const int tid = threadIdx.x;
    __shared__ _Float16 Hs[64 * 34];      // [m][kl] pad row stride 34
    __shared__ _Float16 Ls[64 * 34];

    const float* src = (tensor ? goal : cur) + (size_t)b * CHAN * HW;
#pragma unroll
    for (int i = 0; i < 2; ++i) {
        int f4 = tid + i * 256;           // 0..511
        int kl = f4 >> 4;                 // 0..31
        int m4 = (f4 & 15) * 4;
        float4 v = *(const float4*)(src + (size_t)(kg * 32 + kl) * HW + mt * 64 + m4);
        float vals[4] = {v.x, v.y, v.z, v.w};
#pragma unroll
        for (int e = 0; e < 4; ++e) {
            float f = vals[e] * 64.0f;    // scale to dodge f16 denorms in lo
            _Float16 h = (_Float16)f;
            _Float16 l = (_Float16)(f - (float)h);
            Hs[(m4 + e) * 34 + kl] = h;
            Ls[(m4 + e) * 34 + kl] = l;
        }
    }
    __syncthreads();
    // coalesced writeout: 256 threads x 32B
    const int p    = tid >> 7;            // 0=hi, 1=lo
    const int q    = tid & 127;
    const int m    = q >> 1;
    const int half = q & 1;
    const _Float16* T = p ? Ls : Hs;
    const unsigned* ls = (const unsigned*)&T[m * 34 + half * 16];
    _Float16* plane = tensor ? (p ? pl_goal : ph_goal) : (p ? pl_cur : ph_cur);
    size_t gidx = (((size_t)b * KG + kg) * HW + mt * 64 + m) * 32 + half * 16;
    uint4 u0 = make_uint4(ls[0], ls[1], ls[2], ls[3]);
    uint4 u1 = make_uint4(ls[4], ls[5], ls[6], ls[7]);
    *(uint4*)(plane + gidx)     = u0;
    *(uint4*)(plane + gidx + 8) = u1;
}

// ---------------- 2a. fast MFMA GEMM: f16 hi/lo 3-pass --------------------
// S[b][m][n] = inv_cur*inv_goal/4096 * sum_k (ah*bh + ah*bl + al*bh)
__global__ __launch_bounds__(256)
void gemm_f16_kernel(const _Float16* __restrict__ ph_cur,
                     const _Float16* __restrict__ pl_cur,
                     const _Float16* __restrict__ ph_goal,
                     const _Float16* __restrict__ pl_goal,
                     const float* __restrict__ inv_cur,
                     const float* __restrict__ inv_goal,
                     float* __restrict__ score) {
    const int b  = blockIdx.z;
    const int n0 = blockIdx.x * 128;
    const int m0 = blockIdx.y * 128;
    const int tid  = threadIdx.x;
    const int wid  = tid >> 6;
    const int lane = tid & 63;
    const int ml   = lane & 15;
    const int q8   = (lane >> 4) * 8;
    const int wm   = wid >> 1;
    const int wn   = wid & 1;

    __shared__ _Float16 lds[4 * 4096];   // Ah | Al | Bh | Bl, each 128x32
    _Float16* const Ah = lds;
    _Float16* const Al = lds + 4096;
    _Float16* const Bh = lds + 8192;
    _Float16* const Bl = lds + 12288;

    const size_t aOff0 = ((size_t)b * KG * HW + m0) * 32;
    const size_t bOff0 = ((size_t)b * KG * HW + n0) * 32;
    const _Float16* gplane;
    size_t goff;
    switch (wid) {
        case 0:  gplane = ph_cur;  goff = aOff0; break;
        case 1:  gplane = pl_cur;  goff = aOff0; break;
        case 2:  gplane = ph_goal; goff = bOff0; break;
        default: gplane = pl_goal; goff = bOff0; break;
    }
    _Float16* const lbase = lds + wid * 4096;

    v4f acc[4][4];
#pragma unroll
    for (int mi = 0; mi < 4; ++mi)
#pragma unroll
        for (int ni = 0; ni < 4; ++ni)
            acc[mi][ni] = (v4f)0.0f;

    for (int kg = 0; kg < KG; ++kg) {
        __syncthreads();
        const _Float16* gp = gplane + goff + (size_t)kg * (HW * 32);
#pragma unroll
        for (int i = 0; i < 8; ++i)
            GLDS16(gp + i * 512 + lane * 8, lbase + i * 512 + lane * 8);
        __syncthreads();

        v8h aH[4], aL[4], bH[4], bL[4];
#pragma unroll
        for (int mi = 0; mi < 4; ++mi) {
            int off = (wm * 64 + mi * 16 + ml) * 32 + q8;
            aH[mi] = *(const v8h*)(Ah + off);
            aL[mi] = *(const v8h*)(Al + off);
        }
#pragma unroll
        for (int ni = 0; ni < 4; ++ni) {
            int off = (wn * 64 + ni * 16 + ml) * 32 + q8;
            bH[ni] = *(const v8h*)(Bh + off);
            bL[ni] = *(const v8h*)(Bl + off);
        }
#pragma unroll
        for (int mi = 0; mi < 4; ++mi)
#pragma unroll
            for (int ni = 0; ni < 4; ++ni) {
                acc[mi][ni] = __builtin_amdgcn_mfma_f32_16x16x32_f16(aH[mi], bH[ni], acc[mi][ni], 0, 0, 0);
                acc[mi][ni] = __builtin_amdgcn_mfma_f32_16x16x32_f16(aH[mi], bL[ni], acc[mi][ni], 0, 0, 0);
                acc[mi][ni] = __builtin_amdgcn_mfma_f32_16x16x32_f16(aL[mi], bH[ni], acc[mi][ni], 0, 0, 0);
            }
    }

    // epilogue: row = m0+wm*64+mi*16+(lane>>4)*4+r ; col = n0+wn*64+ni*16+ml
    float inj[4];
#pragma unroll
    for (int ni = 0; ni < 4; ++ni)
        inj[ni] = inv_goal[b * HW + n0 + wn * 64 + ni * 16 + ml] * (1.0f / 4096.0f);
    float* outp = score + (size_t)b * SM_PB;
#pragma unroll
    for (int mi = 0; mi < 4; ++mi) {
#pragma unroll
        for (int r = 0; r < 4; ++r) {
            int row = m0 + wm * 64 + mi * 16 + (lane >> 4) * 4 + r;
            float im = inv_cur[b * HW + row];
#pragma unroll
            for (int ni = 0; ni < 4; ++ni) {
                int col = n0 + wn * 64 + ni * 16 + ml;
                outp[(size_t)row * HW + col] = acc[mi][ni][r] * im * inj[ni];
            }
        }
    }
}

// ---------------- 2b. fallback f32 vector GEMM (round-1, known good) ------
__global__ __launch_bounds__(256)
void gemm_kernel(const float* __restrict__ cur,
                 const float* __restrict__ goal,
                 const float* __restrict__ inv_cur,
                 const float* __restrict__ inv_goal,
                 float* __restrict__ score) {
    const int b  = blockIdx.z;
    const int m0 = blockIdx.x * 64;
    const int n0 = blockIdx.y * 64;
    __shared__ float As[16][64];
    __shared__ float Bs[16][64];
    const int tid = threadIdx.x;
    const int tn = tid & 15;
    const int tm = tid >> 4;
    const int ldk = tid >> 4;
    const int ldc = (tid & 15) * 4;
    const float* A = cur  + (size_t)b * CHAN * HW;
    const float* B = goal + (size_t)b * CHAN * HW;
    float acc[4][4] = {};
    for (int k0 = 0; k0 < CHAN; k0 += 16) {
        __syncthreads();
        *(float4*)&As[ldk][ldc] = *(const float4*)(A + (k0 + ldk) * HW + m0 + ldc);
        *(float4*)&Bs[ldk][ldc] = *(const float4*)(B + (k0 + ldk) * HW + n0 + ldc);
        __syncthreads();
#pragma unroll
        for (int kk = 0; kk < 16; ++kk) {
            float4 a4 = *(float4*)&As[kk][tm * 4];
            float4 b4 = *(float4*)&Bs[kk][tn * 4];
            float a[4] = {a4.x, a4.y, a4.z, a4.w};
            float bb[4] = {b4.x, b4.y, b4.z, b4.w};
#pragma unroll
            for (int i = 0; i < 4; ++i)
#pragma unroll
                for (int j = 0; j < 4; ++j)
                    acc[i][j] += a[i] * bb[j];
        }
    }
    float im[4], inj[4];
#pragma unroll
    for (int i = 0; i < 4; ++i) im[i]  = inv_cur[b * HW + m0 + tm * 4 + i];
#pragma unroll
    for (int j = 0; j < 4; ++j) inj[j] = inv_goal[b * HW + n0 + tn * 4 + j];
    float* outp = score + (size_t)b * SM_PB;
#pragma unroll
    for (int i = 0; i < 4; ++i) {
        int m = m0 + tm * 4 + i;
        float4 v;
        v.x = acc[i][0] * im[i] * inj[0];
        v.y = acc[i][1] * im[i] * inj[1];
        v.z = acc[i][2] * im[i] * inj[2];
        v.w = acc[i][3] * im[i] * inj[3];
        *(float4*)(outp + (size_t)m * HW + n0 + tn * 4) = v;
    }
}

// ---------------- 3. per-batch histogram of key top-12 bits ---------------
__global__ void hist_kernel(const float* __restrict__ score,
                            unsigned* __restrict__ ghist) {
    const int slice = blockIdx.x;
    const int b     = blockIdx.y;
    const int tid   = threadIdx.x;
    __shared__ unsigned hs[NBUCKET];
    for (int i = tid; i < NBUCKET; i += 256) hs[i] = 0;
    __syncthreads();
    const float4* base = (const float4*)(score + (size_t)b * SM_PB + slice * 65536);
    for (int it = 0; it < 64; ++it) {
        float4 v = base[it * 256 + tid];
        atomicAdd(&hs[mono_key(v.x) >> 20], 1u);
        atomicAdd(&hs[mono_key(v.y) >> 20], 1u);
        atomicAdd(&hs[mono_key(v.z) >> 20], 1u);
        atomicAdd(&hs[mono_key(v.w) >> 20], 1u);
    }
    __syncthreads();
    for (int i = tid; i < NBUCKET; i += 256)
        if (hs[i]) atomicAdd(&ghist[b * NBUCKET + i], hs[i]);
}

// ---------------- 4. find threshold bucket per batch (with -1 margin) -----
__global__ void thresh_kernel(const unsigned* __restrict__ ghist,
                              unsigned* __restrict__ tbuf) {
    const int b = blockIdx.x;
    const int tid = threadIdx.x;
    __shared__ unsigned partial[256];
    unsigned s = 0;
    for (int j = 0; j < 16; ++j) s += ghist[b * NBUCKET + tid * 16 + j];
    partial[tid] = s;
    __syncthreads();
    if (tid == 0) {
        unsigned cum = 0;
        int T = 0;
        for (int t = 255; t >= 0; --t) {
            if (cum + partial[t] >= KTOP) {
                for (int k = t * 16 + 15; k >= t * 16; --k) {
                    cum += ghist[b * NBUCKET + k];
                    if (cum >= KTOP) { T = k; break; }
                }
                break;
            }
            cum += partial[t];
        }
        tbuf[b] = (unsigned)(T > 0 ? T - 1 : 0);   // one-bucket safety margin
    }
}

// ---------------- 5. collect candidates (bucket >= T) ---------------------
__global__ void collect_kernel(const float* __restrict__ score,
                               const unsigned* __restrict__ tbuf,
                               unsigned* __restrict__ cnt,
                               unsigned long long* __restrict__ cand) {
    const int slice = blockIdx.x;
    const int b     = blockIdx.y;
    const int tid   = threadIdx.x;
    const int lane  = tid & 63;
    const unsigned T = tbuf[b];
    const float4* base = (const float4*)(score + (size_t)b * SM_PB + slice * 65536);
    for (int it = 0; it < 64; ++it) {
        int e0 = slice * 65536 + (it * 256 + tid) * 4;
        float4 v = base[it * 256 + tid];
        float vals[4] = {v.x, v.y, v.z, v.w};
#pragma unroll
        for (int c = 0; c < 4; ++c) {
            unsigned key = mono_key(vals[c]);
            bool pred = (key >> 20) >= T;
            unsigned long long mask = __ballot(pred);
            if (mask) {
                int lead = __ffsll((unsigned long long)mask) - 1;
                unsigned basep = 0;
                if (lane == lead) basep = atomicAdd(&cnt[b], (unsigned)__popcll(mask));
                basep = __shfl(basep, lead, 64);
                if (pred) {
                    unsigned off = (unsigned)__popcll(mask & ((1ULL << lane) - 1ULL));
                    unsigned pos = basep + off;
                    if (pos < CAND_CAP)
                        cand[(size_t)b * CAND_CAP + pos] =
                            ((unsigned long long)key << 32) |
                            (unsigned long long)(0xFFFFFFFFu - (unsigned)(e0 + c));
                }
            }
        }
    }
}

// ---------------- 6. select top-K (with exact f64 boundary band) ----------
__global__ __launch_bounds__(1024)
void select_kernel(const unsigned long long* __restrict__ cand,
                   const unsigned* __restrict__ cnt,
                   const float* __restrict__ score,
                   const float* __restrict__ cur,
                   const float* __restrict__ goal,
                   float* __restrict__ feats) {
    const int b = blockIdx.x;
    const int tid = threadIdx.x;
    __shared__ unsigned long long arr[CAND_CAP];
    __shared__ unsigned idxs[KTOP];
    __shared__ double rd0[512], rd1[512], rd2[512];
    __shared__ int s_mranks[BAND_CAP];
    __shared__ unsigned long long s_mcomp[BAND_CAP];
    __shared__ double s_mexact[BAND_CAP];
    __shared__ int s_mcount;
    __shared__ int s_np2;

    unsigned n = cnt[b];
    if (n > CAND_CAP) n = CAND_CAP;
    if (tid == 0)
        s_np2 = (n <= 2048u) ? 2048 : ((n <= 4096u) ? 4096 : CAND_CAP);
    __syncthreads();
    const int np2 = s_np2;
    for (int i = tid; i < np2; i += 1024)
        arr[i] = (i < (int)n) ? cand[(size_t)b * CAND_CAP + i] : 0ULL;
    __syncthreads();

    // bitonic sort descending on composite (key desc, idx asc)
    for (unsigned size = 2; size <= (unsigned)np2; size <<= 1) {
        for (unsigned stride = size >> 1; stride > 0; stride >>= 1) {
            for (int i = tid; i < np2; i += 1024) {
                int j = i ^ stride;
                if (j > i) {
                    unsigned long long a = arr[i], c = arr[j];
                    bool desc = ((i & size) == 0);
                    if (desc ? (a < c) : (a > c)) { arr[i] = c; arr[j] = a; }
                }
            }
            __syncthreads();
        }
    }

    // exact f64 recompute of the boundary band around rank K
    if ((int)n > KTOP) {
        if (tid == 0) {
            float vK1 = key_to_float((unsigned)(arr[KTOP - 1] >> 32));
            float vK  = key_to_float((unsigned)(arr[KTOP] >> 32));
            int lo = KTOP - 64; if (lo < 0) lo = 0;
            int hi = KTOP + 64; if (hi > (int)n) hi = n;
            int c = 0;
            for (int r = lo; r < hi && c < BAND_CAP; ++r) {
                float v = key_to_float((unsigned)(arr[r] >> 32));
                if (v <= vK1 + BAND_DELTA && v >= vK - BAND_DELTA) {
                    s_mranks[c] = r;
                    s_mcomp[c] = arr[r];
                    ++c;
                }
            }
            s_mcount = c;
        }
        __syncthreads();
        const int mc = s_mcount;
        for (int j = 0; j < mc; ++j) {
            unsigned idx = 0xFFFFFFFFu - (unsigned)(s_mcomp[j] & 0xFFFFFFFFu);
            int mm = idx >> 10, nn = idx & 1023;
            double pa = 0.0, pb = 0.0, pc = 0.0;
            if (tid < 384) {
                double a = (double)cur [((size_t)b * CHAN + tid) * HW + mm];
                double g = (double)goal[((size_t)b * CHAN + tid) * HW + nn];
                pa = a * g; pb = a * a; pc = g * g;
            }
            if (tid < 512) { rd0[tid] = pa; rd1[tid] = pb; rd2[tid] = pc; }
            __syncthreads();
            for (int s = 256; s >= 1; s >>= 1) {
                if (tid < s) {
                    rd0[tid] += rd0[tid + s];
                    rd1[tid] += rd1[tid + s];
                    rd2[tid] += rd2[tid + s];
                }
                __syncthreads();
            }
            if (tid == 0) {
                double denom = fmax(sqrt(rd1[0]), 1e-12) * fmax(sqrt(rd2[0]), 1e-12);
                s_mexact[j] = rd0[0] / denom;
            }
            __syncthreads();
        }
        if (tid == 0 && mc > 1) {
            // selection sort members by (exact desc, idx asc); write back into slots
            int perm[BAND_CAP];
            for (int i = 0; i < mc; ++i) perm[i] = i;
            for (int i = 0; i < mc - 1; ++i) {
                int best = i;
                for (int k = i + 1; k < mc; ++k) {
                    int pk = perm[k], pb2 = perm[best];
                    unsigned ik = 0xFFFFFFFFu - (unsigned)(s_mcomp[pk] & 0xFFFFFFFFu);
                    unsigned ib = 0xFFFFFFFFu - (unsigned)(s_mcomp[pb2] & 0xFFFFFFFFu);
                    bool better = (s_mexact[pk] > s_mexact[pb2]) ||
                                  (s_mexact[pk] == s_mexact[pb2] && ik < ib);
                    if (better) best = k;
                }
                int t = perm[i]; perm[i] = perm[best]; perm[best] = t;
            }
            for (int i = 0; i < mc; ++i)
                arr[s_mranks[i]] = s_mcomp[perm[i]];
        }
        __syncthreads();
    }

    // top-K indices -> sort ascending by index
    idxs[tid] = 0xFFFFFFFFu - (unsigned)(arr[tid] & 0xFFFFFFFFu);
    __syncthreads();
    for (unsigned size = 2; size <= KTOP; size <<= 1) {
        for (unsigned stride = size >> 1; stride > 0; stride >>= 1) {
            int i = tid;
            int j = i ^ stride;
            if (j > i && i < KTOP) {
                unsigned a = idxs[i], c = idxs[j];
                bool asc = ((i & size) == 0);
                if (asc ? (a > c) : (a < c)) { idxs[i] = c; idxs[j] = a; }
            }
            __syncthreads();
        }
    }

    unsigned idx = idxs[tid];
    float val = score[(size_t)b * SM_PB + idx];
    float* f = feats + (size_t)b * (KTOP * 3) + tid * 3;
    f[0] = (float)(idx >> 10);
    f[1] = (float)(idx & 1023);
    f[2] = val;
}

__device__ __forceinline__ float silu(float x) {
    return x / (1.0f + expf(-x));
}

// ---------------- 7. MLP layer 1: 3072 -> 1024 ----------------------------
__global__ void mlp1_kernel(const float* __restrict__ feats,
                            const float* __restrict__ W1,
                            const float* __restrict__ b1,
                            float* __restrict__ h1) {
    __shared__ float fs[3072];
    const int b = blockIdx.y, chunk = blockIdx.x, tid = threadIdx.x;
    for (int i = tid; i < 3072; i += 256) fs[i] = feats[(size_t)b * 3072 + i];
    __syncthreads();
    const int o = chunk * 256 + tid;
    float acc = b1[o];
    for (int k = 0; k < 3072; ++k) acc += fs[k] * W1[(size_t)k * 1024 + o];
    h1[(size_t)b * 1024 + o] = silu(acc);
}

// ---------------- 8. MLP layer 2: 1024 -> 256 -----------------------------
__global__ void mlp2_kernel(const float* __restrict__ h1,
                            const float* __restrict__ W2,
                            const float* __restrict__ b2,
                            float* __restrict__ h2) {
    __shared__ float hs[1024];
    const int b = blockIdx.x, tid = threadIdx.x;
    for (int i = tid; i < 1024; i += 256) hs[i] = h1[(size_t)b * 1024 + i];
    __syncthreads();
    float acc = b2[tid];
    for (int k = 0; k < 1024; ++k) acc += hs[k] * W2[(size_t)k * 256 + tid];
    h2[(size_t)b * 256 + tid] = silu(acc);
}

// ---------------- 9. MLP tail: 256->64->16->heads -------------------------
__global__ void tail_kernel(const float* __restrict__ h2,
                            const float* __restrict__ W3, const float* __restrict__ b3,
                            const float* __restrict__ W4, const float* __restrict__ b4,
                            const float* __restrict__ Wx, const float* __restrict__ bx,
                            const float* __restrict__ Wy, const float* __restrict__ by,
                            const float* __restrict__ Wr, const float* __restrict__ br,
                            float* __restrict__ action) {
    const int b = blockIdx.x, t = threadIdx.x;  // 64 threads
    __shared__ float h2s[256];
    __shared__ float h3s[64];
    __shared__ float h4s[16];
    for (int i = t; i < 256; i += 64) h2s[i] = h2[(size_t)b * 256 + i];
    __syncthreads();
    {
        float acc = b3[t];
        for (int k = 0; k < 256; ++k) acc += h2s[k] * W3[k * 64 + t];
        h3s[t] = silu(acc);
    }
    __syncthreads();
    if (t < 16) {
        float acc = b4[t];
        for (int k = 0; k < 64; ++k) acc += h3s[k] * W4[k * 16 + t];
        h4s[t] = silu(acc);
    }
    __syncthreads();
    if (t < 9) {
        int head = t / 3, j = t % 3;
        const float* Wh = (head == 0) ? Wx : (head == 1) ? Wy : Wr;
        const float* bh = (head == 0) ? bx : (head == 1) ? by : br;
        float acc = bh[j];
        for (int k = 0; k < 16; ++k) acc += h4s[k] * Wh[k * 3 + j];
        action[b * 9 + t] = acc;
    }
}

extern "C" void kernel_launch(void* const* d_in, const int* in_sizes, int n_in,
                              void* d_out, int out_size, void* d_ws, size_t ws_size,
                              hipStream_t stream) {
    const float* cur  = (const float*)d_in[0];
    const float* goal = (const float*)d_in[1];
    const float* W1 = (const float*)d_in[2];
    const float* b1 = (const float*)d_in[3];
    const float* W2 = (const float*)d_in[4];
    const float* b2 = (const float*)d_in[5];
    const float* W3 = (const float*)d_in[6];
    const float* b3 = (const float*)d_in[7];
    const float* W4 = (const float*)d_in[8];
    const float* b4 = (const float*)d_in[9];
    const float* Wx = (const float*)d_in[10];
    const float* bx = (const float*)d_in[11];
    const float* Wy = (const float*)d_in[12];
    const float* by = (const float*)d_in[13];
    const float* Wr = (const float*)d_in[14];
    const float* br = (const float*)d_in[15];

    float* out = (float*)d_out;
    float* score = out + OUT_OFF;
    char* ws = (char*)d_ws;

    float* inv_cur  = (float*)(ws + WS_INV_CUR);
    float* inv_goal = (float*)(ws + WS_INV_GOAL);
    unsigned* ghist = (unsigned*)(ws + WS_HIST);
    unsigned* cnt   = (unsigned*)(ws + WS_CNT);
    unsigned* tbuf  = (unsigned*)(ws + WS_TBUF);
    unsigned long long* cand = (unsigned long long*)(ws + WS_CAND);
    float* feats = (float*)(ws + WS_FEATS);
    float* h1    = (float*)(ws + WS_H1);
    float* h2    = (float*)(ws + WS_H2);

    hipMemsetAsync(ws + WS_HIST, 0, (size_t)BATCH * NBUCKET * 4 + 512, stream);

    norm_kernel<<<dim3(4, BATCH), 256, 0, stream>>>(cur, goal, inv_cur, inv_goal);

    const bool fast = ws_size >= WS_FAST_NEED;
    if (fast) {
        _Float16* ph_cur  = (_Float16*)(ws + WS_PLANES);
        _Float16* pl_cur  = ph_cur  + PLANE_ELEMS;
        _Float16* ph_goal = pl_cur  + PLANE_ELEMS;
        _Float16* pl_goal = ph_goal + PLANE_ELEMS;
        prep_kernel<<<dim3(16, KG, 128), 256, 0, stream>>>(cur, goal,
                                                           ph_cur, pl_cur, ph_goal, pl_goal);
        gemm_f16_kernel<<<dim3(8, 8, BATCH), 256, 0, stream>>>(ph_cur, pl_cur, ph_goal, pl_goal,
                                                               inv_cur, inv_goal, score);
    } else {
        gemm_kernel<<<dim3(16, 16, BATCH), 256, 0, stream>>>(cur, goal, inv_cur, inv_goal, score);
    }

    hist_kernel<<<dim3(16, BATCH), 256, 0, stream>>>(score, ghist);
    thresh_kernel<<<dim3(BATCH), 256, 0, stream>>>(ghist, tbuf);
    collect_kernel<<<dim3(16, BATCH), 256, 0, stream>>>(score, tbuf, cnt, cand);
    select_kernel<<<dim3(BATCH), 1024, 0, stream>>>(cand, cnt, score, cur, goal, feats);
    mlp1_kernel<<<dim3(4, BATCH), 256, 0, stream>>>(feats, W1, b1, h1);
    mlp2_kernel<<<dim3(BATCH), 256, 0, stream>>>(h1, W2, b2, h2);
    tail_kernel<<<dim3(BATCH), 64, 0, stream>>>(h2, W3, b3, W4, b4,
                                                Wx, bx, Wy, by, Wr, br, out);
}